// Round 12
// baseline (215.835 us; speedup 1.0000x reference)
//
#include <hip/hip_runtime.h>

#define ALPHA 0.1f
#define LOG2E 1.4426950408889634f
#define NJ 4

typedef __attribute__((ext_vector_type(8))) short bf16x8;
typedef __attribute__((ext_vector_type(4))) float f32x4;

// round-to-nearest-even f32 -> bf16 (returns bits in low 16)
__device__ __forceinline__ unsigned int f2bf(float f) {
    unsigned int u = __float_as_uint(f);
    return (u + 0x7FFFu + ((u >> 16) & 1u)) >> 16;
}

__global__ void mmd_zero(float* out) { out[0] = 0.f; }

// ---------------- prep: f32 x,y -> bf16 Z tiles (K-major chunks) + biases ----
// Z layout: z4[tile*1024 + kc*128 + r] = rows tile*128+r, elems kc*8..kc*8+7.
// bias[i] = -alpha*log2e*||z_i||^2 (from the bf16-rounded values).
__global__ __launch_bounds__(256) void mmd_prep(const float* __restrict__ x,
                                                const float* __restrict__ y,
                                                uint4* __restrict__ z4,
                                                float* __restrict__ bias, int N) {
    int t = blockIdx.x * 256 + threadIdx.x;   // one task per (row, kc), 2N*8 tasks
    int row = t >> 3, kc = t & 7;
    const float4* src = (row < N) ? (const float4*)x : (const float4*)y;
    int r = (row < N) ? row : row - N;
    float4 a = src[r * 16 + kc * 2];
    float4 b = src[r * 16 + kc * 2 + 1];
    unsigned int w0 = f2bf(a.x), w1 = f2bf(a.y), w2 = f2bf(a.z), w3 = f2bf(a.w);
    unsigned int w4 = f2bf(b.x), w5 = f2bf(b.y), w6 = f2bf(b.z), w7 = f2bf(b.w);
    uint4 pk;
    pk.x = w0 | (w1 << 16);
    pk.y = w2 | (w3 << 16);
    pk.z = w4 | (w5 << 16);
    pk.w = w6 | (w7 << 16);
    int tile = row >> 7, rr = row & 127;
    z4[tile * 1024 + kc * 128 + rr] = pk;

    float s = 0.f;
    unsigned int ws[8] = {w0, w1, w2, w3, w4, w5, w6, w7};
#pragma unroll
    for (int i = 0; i < 8; ++i) {
        float v = __uint_as_float(ws[i] << 16);
        s = fmaf(v, v, s);
    }
    s += __shfl_xor(s, 1);
    s += __shfl_xor(s, 2);
    s += __shfl_xor(s, 4);
    if (kc == 0) bias[row] = -ALPHA * LOG2E * s;
}

// ---------------- main: round-10 kernel, occupancy raised to 8 blocks/CU ----
// ONLY change vs round-10 mmd_main4: __launch_bounds__(256, 8). VGPR=64 fits
// 8 waves/SIMD exactly (512/64); doubles resident waves to hide L2 latency
// on the per-j B-fragment loads. No LDS tiles, no barriers, no atomics.
__global__ __launch_bounds__(256, 8) void mmd_main4(const uint4* __restrict__ z4,
                                                    const float* __restrict__ bias,
                                                    float* __restrict__ part,
                                                    int T2, int TX) {
    __shared__ float ldsRed[4];

    // block -> (bi, strip): strip u covers bj = bi + u*NJ ...
    int u = blockIdx.x, bi = 0;
    int per = (T2 + NJ - 1) / NJ;
    while (u >= per) { u -= per; ++bi; per = (T2 - bi + NJ - 1) / NJ; }
    int j0 = bi + u * NJ;
    int nj = min(NJ, T2 - j0);

    int tid = threadIdx.x;
    int w = tid >> 6, l = tid & 63;
    int wr = w >> 1, wc = w & 1;          // 2x2 waves, each 64x64 output
    int lrow = l & 15, lk = l >> 4;

    // ---- A fragments + A-bias, direct from global, live all block ----
    const uint4* gA = z4 + bi * 1024;
    bf16x8 af[4][2];
#pragma unroll
    for (int mb = 0; mb < 4; ++mb)
#pragma unroll
        for (int kh = 0; kh < 2; ++kh)
            af[mb][kh] = *(const bf16x8*)(gA + (kh * 4 + lk) * 128 +
                                          wr * 64 + mb * 16 + lrow);
    float bA[4][4];
#pragma unroll
    for (int mb = 0; mb < 4; ++mb)
#pragma unroll
        for (int q = 0; q < 4; ++q)
            bA[mb][q] = bias[bi * 128 + wr * 64 + mb * 16 + lk * 4 + q];

    const float C2 = 2.f * ALPHA * LOG2E;
    float stot = 0.f;

    for (int j = 0; j < nj; ++j) {
        int bj = j0 + j;
        const uint4* gB = z4 + bj * 1024;
        const float* biasB = bias + bj * 128 + wc * 64 + lrow;
        float sp[4] = {0.f, 0.f, 0.f, 0.f};

#pragma unroll
        for (int h = 0; h < 2; ++h) {       // two 64x32 half-passes
            bf16x8 bfr[2][2];
#pragma unroll
            for (int nb = 0; nb < 2; ++nb)
#pragma unroll
                for (int kh = 0; kh < 2; ++kh)
                    bfr[nb][kh] = *(const bf16x8*)(gB + (kh * 4 + lk) * 128 +
                                                   wc * 64 + (h * 2 + nb) * 16 + lrow);
            float ebB[2];
#pragma unroll
            for (int nb = 0; nb < 2; ++nb)
                ebB[nb] = __builtin_amdgcn_exp2f(biasB[(h * 2 + nb) * 16]);

            f32x4 acc[4][2];
#pragma unroll
            for (int mb = 0; mb < 4; ++mb)
#pragma unroll
                for (int nb = 0; nb < 2; ++nb)
                    acc[mb][nb] = (f32x4){0.f, 0.f, 0.f, 0.f};

#pragma unroll
            for (int mb = 0; mb < 4; ++mb) {
#pragma unroll
                for (int nb = 0; nb < 2; ++nb) {
                    acc[mb][nb] = __builtin_amdgcn_mfma_f32_16x16x32_bf16(
                        af[mb][0], bfr[nb][0], acc[mb][nb], 0, 0, 0);
                    acc[mb][nb] = __builtin_amdgcn_mfma_f32_16x16x32_bf16(
                        af[mb][1], bfr[nb][1], acc[mb][nb], 0, 0, 0);
                }
            }

#pragma unroll
            for (int mb = 0; mb < 4; ++mb)
#pragma unroll
                for (int nb = 0; nb < 2; ++nb)
#pragma unroll
                    for (int q = 0; q < 4; ++q) {
                        float e = __builtin_amdgcn_exp2f(
                            fmaf(C2, acc[mb][nb][q], bA[mb][q]));
                        sp[q] = fmaf(ebB[nb], e, sp[q]);
                    }
        }

        float wgt = ((bj == bi) ? 1.f : 2.f) *
                    (((bi < TX) != (bj < TX)) ? -1.f : 1.f);
        stot = fmaf(wgt, (sp[0] + sp[1]) + (sp[2] + sp[3]), stot);
    }

    // ---- reduce: wave shuffle -> LDS -> ONE PLAIN STORE per block ----
#pragma unroll
    for (int off = 32; off > 0; off >>= 1)
        stot += __shfl_down(stot, off, 64);
    if (l == 0) ldsRed[w] = stot;
    __syncthreads();
    if (tid == 0)
        part[blockIdx.x] = ldsRed[0] + ldsRed[1] + ldsRed[2] + ldsRed[3];
}

// ---------------- final: single-block sum of partials -> out[0] -------------
__global__ __launch_bounds__(1024) void mmd_reduce(const float* __restrict__ part,
                                                   float* __restrict__ out, int n) {
    __shared__ float red[16];
    int tid = threadIdx.x;
    float s = 0.f;
    for (int i = tid; i < n; i += 1024) s += part[i];
#pragma unroll
    for (int off = 32; off > 0; off >>= 1)
        s += __shfl_down(s, off, 64);
    int w = tid >> 6, l = tid & 63;
    if (l == 0) red[w] = s;
    __syncthreads();
    if (tid == 0) {
        float t = 0.f;
#pragma unroll
        for (int i = 0; i < 16; ++i) t += red[i];
        out[0] = t;
    }
}

// ---------------- fallback (round-2 proven kernel, used if ws too small) ----
__global__ __launch_bounds__(256) void mmd_main(const float* __restrict__ x,
                                                const float* __restrict__ y,
                                                float* __restrict__ out, int T) {
    __shared__ uint4 ldsT[4][1024];
    __shared__ float ldsB[4][128];
    __shared__ float ldsRed[4];

    int u = blockIdx.x, bi = 0, rem = T;
    while (u >= rem) { u -= rem; ++bi; --rem; }
    int bj = bi + u;
    bool diag = (bi == bj);

    int tid = threadIdx.x;
    int RI = bi * 128, RJ = bj * 128;

    const float4* x4 = (const float4*)x;
    const float4* y4 = (const float4*)y;
#pragma unroll
    for (int p = 0; p < 16; ++p) {
        int task = p * 256 + tid;
        int buf = task >> 10;
        int q = task & 1023;
        int row = q >> 3, kc = q & 7;
        int base = (buf & 1) ? RJ : RI;
        const float4* src = (buf < 2) ? x4 : y4;
        float4 a = src[(base + row) * 16 + kc * 2];
        float4 b = src[(base + row) * 16 + kc * 2 + 1];
        uint4 pk;
        pk.x = f2bf(a.x) | (f2bf(a.y) << 16);
        pk.y = f2bf(a.z) | (f2bf(a.w) << 16);
        pk.z = f2bf(b.x) | (f2bf(b.y) << 16);
        pk.w = f2bf(b.z) | (f2bf(b.w) << 16);
        ldsT[buf][kc * 128 + row] = pk;
    }
    __syncthreads();

#pragma unroll
    for (int p = 0; p < 2; ++p) {
        int task = p * 256 + tid;
        int buf = task >> 7, row = task & 127;
        float s = 0.f;
#pragma unroll
        for (int kc = 0; kc < 8; ++kc) {
            uint4 v = ldsT[buf][kc * 128 + row];
            unsigned int wds[4] = {v.x, v.y, v.z, v.w};
#pragma unroll
            for (int i = 0; i < 4; ++i) {
                float lo = __uint_as_float(wds[i] << 16);
                float hi = __uint_as_float(wds[i] & 0xFFFF0000u);
                s = fmaf(lo, lo, s);
                s = fmaf(hi, hi, s);
            }
        }
        ldsB[buf][row] = -ALPHA * LOG2E * s;
    }
    __syncthreads();

    int w = tid >> 6, l = tid & 63;
    int wr = w >> 1, wc = w & 1;
    int lrow = l & 15, lk = l >> 4;

    const int aBufs[4] = {0, 2, 0, 1};
    const int bBufs[4] = {1, 3, 3, 2};
    float wKL = diag ? 1.f : 2.f;
    const float wts[4] = {wKL, wKL, -2.f, -2.f};
    int npass = diag ? 3 : 4;

    const float C2 = 2.f * ALPHA * LOG2E;
    float stot = 0.f;

    for (int ps = 0; ps < npass; ++ps) {
        int ab = aBufs[ps], bb = bBufs[ps];
        bf16x8 af[4][2], bfr[4][2];
#pragma unroll
        for (int mb = 0; mb < 4; ++mb) {
#pragma unroll
            for (int kh = 0; kh < 2; ++kh) {
                int ar = wr * 64 + mb * 16 + lrow;
                int br = wc * 64 + mb * 16 + lrow;
                int kc = kh * 4 + lk;
                af[mb][kh]  = *(const bf16x8*)&ldsT[ab][kc * 128 + ar];
                bfr[mb][kh] = *(const bf16x8*)&ldsT[bb][kc * 128 + br];
            }
        }
        f32x4 acc[4][4];
#pragma unroll
        for (int mb = 0; mb < 4; ++mb)
#pragma unroll
            for (int nb = 0; nb < 4; ++nb)
                acc[mb][nb] = (f32x4){0.f, 0.f, 0.f, 0.f};
#pragma unroll
        for (int mb = 0; mb < 4; ++mb) {
#pragma unroll
            for (int nb = 0; nb < 4; ++nb) {
                acc[mb][nb] = __builtin_amdgcn_mfma_f32_16x16x32_bf16(
                    af[mb][0], bfr[nb][0], acc[mb][nb], 0, 0, 0);
                acc[mb][nb] = __builtin_amdgcn_mfma_f32_16x16x32_bf16(
                    af[mb][1], bfr[nb][1], acc[mb][nb], 0, 0, 0);
            }
        }
        float bA[4][4], bB[4];
#pragma unroll
        for (int mb = 0; mb < 4; ++mb)
#pragma unroll
            for (int q = 0; q < 4; ++q)
                bA[mb][q] = ldsB[ab][wr * 64 + mb * 16 + lk * 4 + q];
#pragma unroll
        for (int nb = 0; nb < 4; ++nb)
            bB[nb] = ldsB[bb][wc * 64 + nb * 16 + lrow];
        float sp = 0.f;
#pragma unroll
        for (int mb = 0; mb < 4; ++mb) {
#pragma unroll
            for (int nb = 0; nb < 4; ++nb) {
#pragma unroll
                for (int q = 0; q < 4; ++q) {
                    float arg = fmaf(C2, acc[mb][nb][q], bA[mb][q] + bB[nb]);
                    sp += __builtin_amdgcn_exp2f(arg);
                }
            }
        }
        stot = fmaf(wts[ps], sp, stot);
    }

#pragma unroll
    for (int off = 32; off > 0; off >>= 1)
        stot += __shfl_down(stot, off, 64);
    if (l == 0) ldsRed[w] = stot;
    __syncthreads();
    if (tid == 0)
        atomicAdd(out, ldsRed[0] + ldsRed[1] + ldsRed[2] + ldsRed[3]);
}

extern "C" void kernel_launch(void* const* d_in, const int* in_sizes, int n_in,
                              void* d_out, int out_size, void* d_ws, size_t ws_size,
                              hipStream_t stream) {
    (void)n_in; (void)out_size;
    const float* x = (const float*)d_in[0];
    const float* y = (const float*)d_in[1];
    float* out = (float*)d_out;

    int N = in_sizes[0] / 64;               // 8192
    int T2 = (2 * N) / 128;                 // 128 tiles over Z
    int TX = N / 128;
    int mainBlocks = 0;
    for (int bi = 0; bi < T2; ++bi) mainBlocks += (T2 - bi + NJ - 1) / NJ;

    size_t zBytes = (size_t)2 * N * 128;    // 2N rows x 128B bf16
    size_t bBytes = (size_t)2 * N * 4;
    size_t need = zBytes + bBytes + (size_t)mainBlocks * 4;

    if (ws_size >= need) {
        uint4* z4 = (uint4*)d_ws;
        float* bias = (float*)((char*)d_ws + zBytes);
        float* part = (float*)((char*)d_ws + zBytes + bBytes);
        int prepBlocks = (2 * N * 8) / 256; // 512
        hipLaunchKernelGGL(mmd_prep, dim3(prepBlocks), dim3(256), 0, stream,
                           x, y, z4, bias, N);
        hipLaunchKernelGGL(mmd_main4, dim3(mainBlocks), dim3(256), 0, stream,
                           z4, bias, part, T2, TX);
        hipLaunchKernelGGL(mmd_reduce, dim3(1), dim3(1024), 0, stream,
                           part, out, mainBlocks);
    } else {
        int T = N / 128;
        int nblocks = T * (T + 1) / 2;
        hipLaunchKernelGGL(mmd_zero, dim3(1), dim3(1), 0, stream, out);
        hipLaunchKernelGGL(mmd_main, dim3(nblocks), dim3(256), 0, stream,
                           x, y, out, T);
    }
}

// Round 13
// 39.332 us; speedup vs baseline: 5.4875x; 5.4875x over previous
//
#include <hip/hip_runtime.h>

#define ALPHA 0.1f
#define LOG2E 1.4426950408889634f
#define NJ 8

typedef __attribute__((ext_vector_type(8))) short bf16x8;
typedef __attribute__((ext_vector_type(4))) float f32x4;

// round-to-nearest-even f32 -> bf16 (returns bits in low 16)
__device__ __forceinline__ unsigned int f2bf(float f) {
    unsigned int u = __float_as_uint(f);
    return (u + 0x7FFFu + ((u >> 16) & 1u)) >> 16;
}

__global__ void mmd_zero(float* out) { out[0] = 0.f; }

// ---------------- prep: f32 x,y -> bf16 Z tiles (K-major chunks) + biases ----
// Z layout: z4[tile*1024 + kc*128 + r] = rows tile*128+r, elems kc*8..kc*8+7.
// bias[i] = -alpha*log2e*||z_i||^2 (from the bf16-rounded values).
__global__ __launch_bounds__(256) void mmd_prep(const float* __restrict__ x,
                                                const float* __restrict__ y,
                                                uint4* __restrict__ z4,
                                                float* __restrict__ bias, int N) {
    int t = blockIdx.x * 256 + threadIdx.x;   // one task per (row, kc), 2N*8 tasks
    int row = t >> 3, kc = t & 7;
    const float4* src = (row < N) ? (const float4*)x : (const float4*)y;
    int r = (row < N) ? row : row - N;
    float4 a = src[r * 16 + kc * 2];
    float4 b = src[r * 16 + kc * 2 + 1];
    unsigned int w0 = f2bf(a.x), w1 = f2bf(a.y), w2 = f2bf(a.z), w3 = f2bf(a.w);
    unsigned int w4 = f2bf(b.x), w5 = f2bf(b.y), w6 = f2bf(b.z), w7 = f2bf(b.w);
    uint4 pk;
    pk.x = w0 | (w1 << 16);
    pk.y = w2 | (w3 << 16);
    pk.z = w4 | (w5 << 16);
    pk.w = w6 | (w7 << 16);
    int tile = row >> 7, rr = row & 127;
    z4[tile * 1024 + kc * 128 + rr] = pk;

    float s = 0.f;
    unsigned int ws[8] = {w0, w1, w2, w3, w4, w5, w6, w7};
#pragma unroll
    for (int i = 0; i < 8; ++i) {
        float v = __uint_as_float(ws[i] << 16);
        s = fmaf(v, v, s);
    }
    s += __shfl_xor(s, 1);
    s += __shfl_xor(s, 2);
    s += __shfl_xor(s, 4);
    if (kc == 0) bias[row] = -ALPHA * LOG2E * s;
}

// ---------------- main: half-pass software pipeline, NJ=8 strip -------------
// Round-10 structure (no LDS tiles, no barriers, plain part[] store) with the
// j-loop fully unrolled into 2*NJ half-passes. Ping-pong frag[2][..] registers:
// half t+1's 4 B-fragment loads issue BEFORE half t's MFMA+epilogue (~800 cyc)
// so the ~200-400cyc L2 latency is hidden by ILP. Tail strips live-masked
// (wgt=0) so every register index is compile-time (no scratch).
__global__ __launch_bounds__(256, 4) void mmd_main6(const uint4* __restrict__ z4,
                                                    const float* __restrict__ bias,
                                                    float* __restrict__ part,
                                                    int T2, int TX) {
    __shared__ float ldsRed[4];

    // block -> (bi, strip): strip u covers bj = j0 .. j0+nj-1
    int u = blockIdx.x, bi = 0;
    int per = (T2 + NJ - 1) / NJ;
    while (u >= per) { u -= per; ++bi; per = (T2 - bi + NJ - 1) / NJ; }
    int j0 = bi + u * NJ;
    int nj = min(NJ, T2 - j0);

    int tid = threadIdx.x;
    int w = tid >> 6, l = tid & 63;
    int wr = w >> 1, wc = w & 1;          // 2x2 waves, each 64x64 output
    int lrow = l & 15, lk = l >> 4;

    // ---- A fragments + A-bias, live for the whole strip ----
    const uint4* gA = z4 + bi * 1024;
    bf16x8 af[4][2];
#pragma unroll
    for (int mb = 0; mb < 4; ++mb)
#pragma unroll
        for (int kh = 0; kh < 2; ++kh)
            af[mb][kh] = *(const bf16x8*)(gA + (kh * 4 + lk) * 128 +
                                          wr * 64 + mb * 16 + lrow);
    float bA[4][4];
#pragma unroll
    for (int mb = 0; mb < 4; ++mb)
#pragma unroll
        for (int q = 0; q < 4; ++q)
            bA[mb][q] = bias[bi * 128 + wr * 64 + mb * 16 + lk * 4 + q];

    const float C2 = 2.f * ALPHA * LOG2E;
    float stot = 0.f;

    // per-lane constant part of the B-fragment offset
    int fragBase = wc * 64 + lrow;

    bf16x8 frag[2][2][2];   // [parity][nb][kh] — parity static after unroll

    // prologue: load half 0 (j=0 always live)
    {
        const uint4* gB = z4 + j0 * 1024;
#pragma unroll
        for (int nb = 0; nb < 2; ++nb)
#pragma unroll
            for (int kh = 0; kh < 2; ++kh)
                frag[0][nb][kh] = *(const bf16x8*)(gB + (kh * 4 + lk) * 128 +
                                                   fragBase + nb * 16);
    }

#pragma unroll
    for (int t = 0; t < 2 * NJ; ++t) {
        const int j = t >> 1, h = t & 1, cp = t & 1;
        bool live = (j < nj);
        int bj = live ? (j0 + j) : j0;

        // ---- prefetch half t+1 into the other parity (before any compute) --
        if (t + 1 < 2 * NJ) {
            const int jn = (t + 1) >> 1, hn = (t + 1) & 1;
            int bjn = (jn < nj) ? (j0 + jn) : j0;
            const uint4* gBn = z4 + bjn * 1024;
#pragma unroll
            for (int nb = 0; nb < 2; ++nb)
#pragma unroll
                for (int kh = 0; kh < 2; ++kh)
                    frag[cp ^ 1][nb][kh] =
                        *(const bf16x8*)(gBn + (kh * 4 + lk) * 128 +
                                         fragBase + (hn * 2 + nb) * 16);
        }

        // ---- this half's B-side bias factors ----
        const float* biasB = bias + bj * 128 + wc * 64 + lrow;
        float ebB0 = __builtin_amdgcn_exp2f(biasB[(h * 2 + 0) * 16]);
        float ebB1 = __builtin_amdgcn_exp2f(biasB[(h * 2 + 1) * 16]);

        // ---- MFMA on current parity ----
        f32x4 acc[4][2];
#pragma unroll
        for (int mb = 0; mb < 4; ++mb)
#pragma unroll
            for (int nb = 0; nb < 2; ++nb)
                acc[mb][nb] = (f32x4){0.f, 0.f, 0.f, 0.f};
#pragma unroll
        for (int mb = 0; mb < 4; ++mb) {
#pragma unroll
            for (int nb = 0; nb < 2; ++nb) {
                acc[mb][nb] = __builtin_amdgcn_mfma_f32_16x16x32_bf16(
                    af[mb][0], frag[cp][nb][0], acc[mb][nb], 0, 0, 0);
                acc[mb][nb] = __builtin_amdgcn_mfma_f32_16x16x32_bf16(
                    af[mb][1], frag[cp][nb][1], acc[mb][nb], 0, 0, 0);
            }
        }

        // ---- epilogue: term = exp2(C2*dot + bA) * exp2(bB) ----
        float sp[4] = {0.f, 0.f, 0.f, 0.f};
#pragma unroll
        for (int mb = 0; mb < 4; ++mb) {
#pragma unroll
            for (int nb = 0; nb < 2; ++nb) {
                float eb = nb ? ebB1 : ebB0;
#pragma unroll
                for (int q = 0; q < 4; ++q) {
                    float e = __builtin_amdgcn_exp2f(
                        fmaf(C2, acc[mb][nb][q], bA[mb][q]));
                    sp[q] = fmaf(eb, e, sp[q]);
                }
            }
        }

        float wgt = live ? (((bj == bi) ? 1.f : 2.f) *
                            (((bi < TX) != (bj < TX)) ? -1.f : 1.f))
                         : 0.f;
        stot = fmaf(wgt, (sp[0] + sp[1]) + (sp[2] + sp[3]), stot);
    }

    // ---- reduce: wave shuffle -> LDS -> one plain store per block ----
#pragma unroll
    for (int off = 32; off > 0; off >>= 1)
        stot += __shfl_down(stot, off, 64);
    if (l == 0) ldsRed[w] = stot;
    __syncthreads();
    if (tid == 0)
        part[blockIdx.x] = ldsRed[0] + ldsRed[1] + ldsRed[2] + ldsRed[3];
}

// ---------------- final: single-block sum of partials -> out[0] -------------
__global__ __launch_bounds__(1024) void mmd_reduce(const float* __restrict__ part,
                                                   float* __restrict__ out, int n) {
    __shared__ float red[16];
    int tid = threadIdx.x;
    float s = 0.f;
    for (int i = tid; i < n; i += 1024) s += part[i];
#pragma unroll
    for (int off = 32; off > 0; off >>= 1)
        s += __shfl_down(s, off, 64);
    int w = tid >> 6, l = tid & 63;
    if (l == 0) red[w] = s;
    __syncthreads();
    if (tid == 0) {
        float t = 0.f;
#pragma unroll
        for (int i = 0; i < 16; ++i) t += red[i];
        out[0] = t;
    }
}

// ---------------- fallback (round-2 proven kernel, used if ws too small) ----
__global__ __launch_bounds__(256) void mmd_main(const float* __restrict__ x,
                                                const float* __restrict__ y,
                                                float* __restrict__ out, int T) {
    __shared__ uint4 ldsT[4][1024];
    __shared__ float ldsB[4][128];
    __shared__ float ldsRed[4];

    int u = blockIdx.x, bi = 0, rem = T;
    while (u >= rem) { u -= rem; ++bi; --rem; }
    int bj = bi + u;
    bool diag = (bi == bj);

    int tid = threadIdx.x;
    int RI = bi * 128, RJ = bj * 128;

    const float4* x4 = (const float4*)x;
    const float4* y4 = (const float4*)y;
#pragma unroll
    for (int p = 0; p < 16; ++p) {
        int task = p * 256 + tid;
        int buf = task >> 10;
        int q = task & 1023;
        int row = q >> 3, kc = q & 7;
        int base = (buf & 1) ? RJ : RI;
        const float4* src = (buf < 2) ? x4 : y4;
        float4 a = src[(base + row) * 16 + kc * 2];
        float4 b = src[(base + row) * 16 + kc * 2 + 1];
        uint4 pk;
        pk.x = f2bf(a.x) | (f2bf(a.y) << 16);
        pk.y = f2bf(a.z) | (f2bf(a.w) << 16);
        pk.z = f2bf(b.x) | (f2bf(b.y) << 16);
        pk.w = f2bf(b.z) | (f2bf(b.w) << 16);
        ldsT[buf][kc * 128 + row] = pk;
    }
    __syncthreads();

#pragma unroll
    for (int p = 0; p < 2; ++p) {
        int task = p * 256 + tid;
        int buf = task >> 7, row = task & 127;
        float s = 0.f;
#pragma unroll
        for (int kc = 0; kc < 8; ++kc) {
            uint4 v = ldsT[buf][kc * 128 + row];
            unsigned int wds[4] = {v.x, v.y, v.z, v.w};
#pragma unroll
            for (int i = 0; i < 4; ++i) {
                float lo = __uint_as_float(wds[i] << 16);
                float hi = __uint_as_float(wds[i] & 0xFFFF0000u);
                s = fmaf(lo, lo, s);
                s = fmaf(hi, hi, s);
            }
        }
        ldsB[buf][row] = -ALPHA * LOG2E * s;
    }
    __syncthreads();

    int w = tid >> 6, l = tid & 63;
    int wr = w >> 1, wc = w & 1;
    int lrow = l & 15, lk = l >> 4;

    const int aBufs[4] = {0, 2, 0, 1};
    const int bBufs[4] = {1, 3, 3, 2};
    float wKL = diag ? 1.f : 2.f;
    const float wts[4] = {wKL, wKL, -2.f, -2.f};
    int npass = diag ? 3 : 4;

    const float C2 = 2.f * ALPHA * LOG2E;
    float stot = 0.f;

    for (int ps = 0; ps < npass; ++ps) {
        int ab = aBufs[ps], bb = bBufs[ps];
        bf16x8 af[4][2], bfr[4][2];
#pragma unroll
        for (int mb = 0; mb < 4; ++mb) {
#pragma unroll
            for (int kh = 0; kh < 2; ++kh) {
                int ar = wr * 64 + mb * 16 + lrow;
                int br = wc * 64 + mb * 16 + lrow;
                int kc = kh * 4 + lk;
                af[mb][kh]  = *(const bf16x8*)&ldsT[ab][kc * 128 + ar];
                bfr[mb][kh] = *(const bf16x8*)&ldsT[bb][kc * 128 + br];
            }
        }
        f32x4 acc[4][4];
#pragma unroll
        for (int mb = 0; mb < 4; ++mb)
#pragma unroll
            for (int nb = 0; nb < 4; ++nb)
                acc[mb][nb] = (f32x4){0.f, 0.f, 0.f, 0.f};
#pragma unroll
        for (int mb = 0; mb < 4; ++mb) {
#pragma unroll
            for (int nb = 0; nb < 4; ++nb) {
                acc[mb][nb] = __builtin_amdgcn_mfma_f32_16x16x32_bf16(
                    af[mb][0], bfr[nb][0], acc[mb][nb], 0, 0, 0);
                acc[mb][nb] = __builtin_amdgcn_mfma_f32_16x16x32_bf16(
                    af[mb][1], bfr[nb][1], acc[mb][nb], 0, 0, 0);
            }
        }
        float bA[4][4], bB[4];
#pragma unroll
        for (int mb = 0; mb < 4; ++mb)
#pragma unroll
            for (int q = 0; q < 4; ++q)
                bA[mb][q] = ldsB[ab][wr * 64 + mb * 16 + lk * 4 + q];
#pragma unroll
        for (int nb = 0; nb < 4; ++nb)
            bB[nb] = ldsB[bb][wc * 64 + nb * 16 + lrow];
        float sp = 0.f;
#pragma unroll
        for (int mb = 0; mb < 4; ++mb) {
#pragma unroll
            for (int nb = 0; nb < 4; ++nb) {
#pragma unroll
                for (int q = 0; q < 4; ++q) {
                    float arg = fmaf(C2, acc[mb][nb][q], bA[mb][q] + bB[nb]);
                    sp += __builtin_amdgcn_exp2f(arg);
                }
            }
        }
        stot = fmaf(wts[ps], sp, stot);
    }

#pragma unroll
    for (int off = 32; off > 0; off >>= 1)
        stot += __shfl_down(stot, off, 64);
    if (l == 0) ldsRed[w] = stot;
    __syncthreads();
    if (tid == 0)
        atomicAdd(out, ldsRed[0] + ldsRed[1] + ldsRed[2] + ldsRed[3]);
}

extern "C" void kernel_launch(void* const* d_in, const int* in_sizes, int n_in,
                              void* d_out, int out_size, void* d_ws, size_t ws_size,
                              hipStream_t stream) {
    (void)n_in; (void)out_size;
    const float* x = (const float*)d_in[0];
    const float* y = (const float*)d_in[1];
    float* out = (float*)d_out;

    int N = in_sizes[0] / 64;               // 8192
    int T2 = (2 * N) / 128;                 // 128 tiles over Z
    int TX = N / 128;
    int mainBlocks = 0;
    for (int bi = 0; bi < T2; ++bi) mainBlocks += (T2 - bi + NJ - 1) / NJ;

    size_t zBytes = (size_t)2 * N * 128;    // 2N rows x 128B bf16
    size_t bBytes = (size_t)2 * N * 4;
    size_t need = zBytes + bBytes + (size_t)mainBlocks * 4;

    if (ws_size >= need) {
        uint4* z4 = (uint4*)d_ws;
        float* bias = (float*)((char*)d_ws + zBytes);
        float* part = (float*)((char*)d_ws + zBytes + bBytes);
        int prepBlocks = (2 * N * 8) / 256; // 512
        hipLaunchKernelGGL(mmd_prep, dim3(prepBlocks), dim3(256), 0, stream,
                           x, y, z4, bias, N);
        hipLaunchKernelGGL(mmd_main6, dim3(mainBlocks), dim3(256), 0, stream,
                           z4, bias, part, T2, TX);
        hipLaunchKernelGGL(mmd_reduce, dim3(1), dim3(1024), 0, stream,
                           part, out, mainBlocks);
    } else {
        int T = N / 128;
        int nblocks = T * (T + 1) / 2;
        hipLaunchKernelGGL(mmd_zero, dim3(1), dim3(1), 0, stream, out);
        hipLaunchKernelGGL(mmd_main, dim3(nblocks), dim3(256), 0, stream,
                           x, y, out, T);
    }
}